// Round 10
// baseline (827.491 us; speedup 1.0000x reference)
//
#include <hip/hip_runtime.h>

// ---------------------------------------------------------------------------
// UAActor MC-dropout ADF MLP, MI355X/gfx950.
// B=32768 S=512 H1=400 H2=300 A=8 N=3.  Inputs bf16 (runtime-detected; f32
// fallback).  Internal GEMM operands bf16.
//
// R14 == R13 resubmit (round-9 bench was an infra failure — third of its
// kind; rounds 1 and 6 failed identically and their verbatim resubmits
// passed.  Audit of the new fused Phase A/B found: W1 col ≤ 399 by
// construction, x reads in range, LDS writes < 13056 with exact 4-wave
// partition of cols 0..399, register phases sequential).
// R13: FULL FUSION — k_l1 and the omov intermediate deleted.  Each k_l23f
// block (n, 32-row tile) computes layer-1 itself (x 32KB + W1 400KB, both
// L2-resident across the 3 n-siblings), ADF+mask1 straight into pm/pv LDS
// slabs, then layers 2+3 verbatim from R8.  Saves omov 52MB write + 157MB
// read + a whole dispatch; costs 3x layer-1 MFMA (cheap at 9% MfmaUtil).
// ---------------------------------------------------------------------------

typedef unsigned short u16;
typedef unsigned int u32;
typedef float f32x4 __attribute__((ext_vector_type(4)));
typedef __bf16 bf16x8 __attribute__((ext_vector_type(8)));
typedef u32 u32x4 __attribute__((ext_vector_type(4)));

union U4 { u32x4 u; bf16x8 v; u16 s[8]; };

#define MFMA16(a, b, c) __builtin_amdgcn_mfma_f32_16x16x32_bf16(a, b, c, 0, 0, 0)

#define B_N 32768
#define S_N 512
#define H1_N 400
#define H2_N 300
#define A_N 8

__device__ __forceinline__ float bf2f(u16 h) {
    union { float f; u32 u; } c; c.u = ((u32)h) << 16; return c.f;
}
// Native HW convert (RNE, v_cvt_pk_bf16_f32 when paired).
__device__ __forceinline__ u16 f2bfbits(float f) {
    union { __bf16 h; u16 u; } c; c.h = (__bf16)f; return c.u;
}
__device__ __forceinline__ u32 encf(float f) {
    u32 u = __float_as_uint(f);
    return (u & 0x80000000u) ? ~u : (u | 0x80000000u);
}
__device__ __forceinline__ float decf(u32 e) {
    u32 u = (e >> 31) ? (e & 0x7FFFFFFFu) : ~e;
    return __uint_as_float(u);
}

// ADF ReLU moment matching; shares one exp between erf (A&S 7.1.26) and pdf.
__device__ __forceinline__ void adf_relu(float m, float v, float& om, float& ov) {
    v = fmaxf(v, 1e-12f);
    float rstd = rsqrtf(v);
    float stdv = v * rstd;
    float r = m * rstd;
    float e = __expf(-0.5f * r * r);
    float ar = fabsf(r) * 0.70710678118654752f;
    float t = __builtin_amdgcn_rcpf(fmaf(0.3275911f, ar, 1.0f));
    float poly = t * (0.254829592f + t * (-0.284496736f + t * (1.421413741f +
                  t * (-1.453152027f + t * 1.061405429f))));
    float erfa = 1.0f - poly * e;
    float erfv = (r < 0.0f) ? -erfa : erfa;
    float cdf = 0.5f * (1.0f + erfv);
    float pdf = 0.3989422804014327f * e;
    om = fmaf(m, cdf, stdv * pdf);
    ov = fmaf(m * m + v, cdf, m * stdv * pdf) - om * om;
    ov = fmaxf(ov, 0.0f);
}

// ---------------- workspace layout (bytes) ----------------
#define WS_CTL    0u          // u32[16]: [0]=is_bf16, [1]=encmin, [2]=encmax
#define WS_B1F    64u         // 400 f32
#define WS_B2F    1664u       // 300 f32
#define WS_B3F    2880u       // 8 f32
#define WS_RS1    2944u       // 400 f32
#define WS_VC1    4544u       // 400 f32
#define WS_W3M    6144u       // 16*320 bf16 (zero padded)
#define WS_W3V    16384u      // 16*320 bf16 (squares)
#define WS_W2SQ   26624u      // 300*400 bf16
#define WS_W2B    266624u     // 300*400 bf16 (f32 mode: converted W2)
#define WS_W1B    506624u     // 400*512 bf16 (f32 mode: converted W1)
#define WS_MP     53345024u   // 3*32768*8 f32 per-n mean partials (3145728 B)
#define WS_VP     56490752u   // 3*32768*8 f32 per-n var partials, end 59636480

// ---------------- dtype detect + ctl init ----------------
__global__ void k_detect(const u32* __restrict__ xw, u32* __restrict__ ctl) {
    if (threadIdx.x == 0) {
        int votes = 0;
        for (int i = 0; i < 64; ++i) {
            u32 u = xw[i * 997];
            u32 e = (u >> 7) & 0xFFu;
            votes += (e >= 100u && e <= 145u) ? 1 : 0;
        }
        ctl[0] = (votes >= 40) ? 1u : 0u;
        ctl[1] = 0xFFFFFFFFu;   // encoded min slot
        ctl[2] = 0u;            // encoded max slot
    }
}

// ---------------- weights prep (both modes) ----------------
__global__ void k_weights(const void* __restrict__ w1r, const void* __restrict__ w2r,
                          const void* __restrict__ w3r, const void* __restrict__ b1r,
                          const void* __restrict__ b2r, const void* __restrict__ b3r,
                          const u32* __restrict__ ctl,
                          u16* __restrict__ w1b, u16* __restrict__ w2b,
                          u16* __restrict__ w2sq, u16* __restrict__ w3m,
                          u16* __restrict__ w3v, float* __restrict__ b1f,
                          float* __restrict__ b2f, float* __restrict__ b3f) {
    const bool bf = ctl[0] != 0u;
    const int t = blockIdx.x * 256 + threadIdx.x;

    if (t < (H2_N * H1_N / 8)) {  // W2 -> w2sq (+ W2B in f32 mode)
        float f[8];
        if (bf) {
            U4 d; d.u = *(const u32x4*)((const u16*)w2r + (size_t)t * 8);
            #pragma unroll
            for (int j = 0; j < 8; ++j) f[j] = bf2f(d.s[j]);
        } else {
            f32x4 a = *((const f32x4*)w2r + (size_t)t * 2);
            f32x4 b = *((const f32x4*)w2r + (size_t)t * 2 + 1);
            #pragma unroll
            for (int j = 0; j < 4; ++j) { f[j] = a[j]; f[4 + j] = b[j]; }
        }
        u16 sq[8], cv[8];
        #pragma unroll
        for (int j = 0; j < 8; ++j) { sq[j] = f2bfbits(f[j] * f[j]); cv[j] = f2bfbits(f[j]); }
        *(u32x4*)(w2sq + (size_t)t * 8) = *(u32x4*)sq;
        if (!bf) *(u32x4*)(w2b + (size_t)t * 8) = *(u32x4*)cv;
    }
    if (!bf && t < (H1_N * S_N / 8)) {  // W1 convert (f32 mode only)
        f32x4 a = *((const f32x4*)w1r + (size_t)t * 2);
        f32x4 b = *((const f32x4*)w1r + (size_t)t * 2 + 1);
        u16 cv[8];
        #pragma unroll
        for (int j = 0; j < 4; ++j) { cv[j] = f2bfbits(a[j]); cv[4 + j] = f2bfbits(b[j]); }
        *(u32x4*)(w1b + (size_t)t * 8) = *(u32x4*)cv;
    }
    if (t < 16 * 320) {  // padded W3 tables
        int col = t / 320, k = t - col * 320;
        float f = 0.0f;
        if (col < A_N && k < H2_N)
            f = bf ? bf2f(((const u16*)w3r)[col * H2_N + k]) : ((const float*)w3r)[col * H2_N + k];
        w3m[t] = f2bfbits(f);
        w3v[t] = f2bfbits(f * f);
    }
    if (t < H1_N) b1f[t] = bf ? bf2f(((const u16*)b1r)[t]) : ((const float*)b1r)[t];
    if (t < H2_N) b2f[t] = bf ? bf2f(((const u16*)b2r)[t]) : ((const float*)b2r)[t];
    if (t < A_N)  b3f[t] = bf ? bf2f(((const u16*)b3r)[t]) : ((const float*)b3r)[t];
}

// ---------------- global min/max of x ----------------
__global__ void k_minmax(const void* __restrict__ xr, u32* __restrict__ ctl) {
    const int tid = threadIdx.x, lane = tid & 63, wv = tid >> 6;
    const bool bf = ctl[0] != 0u;
    float mn = 3.0e38f, mx = -3.0e38f;
    const int idx = blockIdx.x * 256 + tid;
    if (bf) {
        const u16* xg = (const u16*)xr;
        for (int i = idx; i < (B_N * S_N / 8); i += 2048 * 256) {
            U4 d; d.u = *(const u32x4*)(xg + (size_t)i * 8);
            #pragma unroll
            for (int j = 0; j < 8; ++j) {
                float f = bf2f(d.s[j]);
                mn = fminf(mn, f); mx = fmaxf(mx, f);
            }
        }
    } else {
        const f32x4* xf = (const f32x4*)xr;
        for (int i = idx; i < (B_N * S_N / 4); i += 2048 * 256) {
            f32x4 d = xf[i];
            #pragma unroll
            for (int j = 0; j < 4; ++j) {
                mn = fminf(mn, d[j]); mx = fmaxf(mx, d[j]);
            }
        }
    }
    #pragma unroll
    for (int off = 32; off >= 1; off >>= 1) {
        mn = fminf(mn, __shfl_xor(mn, off));
        mx = fmaxf(mx, __shfl_xor(mx, off));
    }
    __shared__ float rmn[4], rmx[4];
    if (lane == 0) { rmn[wv] = mn; rmx[wv] = mx; }
    __syncthreads();
    if (tid == 0) {
        for (int w = 1; w < 4; ++w) { mn = fminf(mn, rmn[w]); mx = fmaxf(mx, rmx[w]); }
        atomicMin(&ctl[1], encf(mn));
        atomicMax(&ctl[2], encf(mx));
    }
}

// ---------------- W1 row sums + variance constant ----------------
__global__ void k_prep(const void* __restrict__ w1r, const u32* __restrict__ ctl,
                       float* __restrict__ rs1, float* __restrict__ vc1) {
    const bool bf = ctl[0] != 0u;
    const int h = blockIdx.x, lane = threadIdx.x;
    float f[8];
    if (bf) {
        U4 d; d.u = *(const u32x4*)((const u16*)w1r + (size_t)h * S_N + lane * 8);
        #pragma unroll
        for (int j = 0; j < 8; ++j) f[j] = bf2f(d.s[j]);
    } else {
        f32x4 a = *((const f32x4*)w1r + (size_t)h * 128 + lane * 2);
        f32x4 b = *((const f32x4*)w1r + (size_t)h * 128 + lane * 2 + 1);
        #pragma unroll
        for (int j = 0; j < 4; ++j) { f[j] = a[j]; f[4 + j] = b[j]; }
    }
    float s1 = 0.f, s2 = 0.f;
    #pragma unroll
    for (int j = 0; j < 8; ++j) { s1 += f[j]; s2 += f[j] * f[j]; }
    #pragma unroll
    for (int off = 32; off >= 1; off >>= 1) {
        s1 += __shfl_xor(s1, off);
        s2 += __shfl_xor(s2, off);
    }
    if (lane == 0) { rs1[h] = s1; vc1[h] = 2.0001f * s2; }
}

// ---------------- FUSED layers 1+2+3, one (n, row-tile) per block ----------------
// grid 3072 = 1024 row-tiles x 3 MC samples, n fastest (x/W1 L2 reuse across
// the 3 co-dispatched siblings).  Phase A: layer-1 GEMM x[32][512] @ W1^T,
// col split 7/6/6/6 tiles/wave (= 400 exactly).  Phase B: ADF + mask1 ->
// pm/pv LDS slabs directly (MFMA C layout: col = layer-2 k-dim).  Phases
// C-E: R8 k_l23 verbatim (layer-2 GEMM, ADF+mask2, W3, f32 partials).
__global__ __launch_bounds__(256, 3)
void k_l23f(const void* __restrict__ xr, const u16* __restrict__ w1bf,
            const u16* __restrict__ w1cv, const float* __restrict__ b1f,
            const float* __restrict__ rs1, const float* __restrict__ vc1,
            const u16* __restrict__ w2bf, const u16* __restrict__ w2cv,
            const u16* __restrict__ w2sqg,
            const void* __restrict__ m1r, const void* __restrict__ m2r,
            const float* __restrict__ b2f,
            const u16* __restrict__ w3mg, const u16* __restrict__ w3vg,
            const u32* __restrict__ ctl, float* __restrict__ mpart,
            float* __restrict__ vpart) {
    __shared__ __align__(16) unsigned char smem[52224];
    u16* pmS = (u16*)smem;                 // [32][408] bf16 products
    u16* pvS = (u16*)(smem + 26112);       // [32][408]
    u16* m2s = (u16*)smem;                 // [32][328] (aliases pmS, post-GEMM)
    u16* v2s = (u16*)(smem + 26112);       // [32][328] (aliases pvS)

    const int tid = threadIdx.x;
    const int wv = tid >> 6, lane = tid & 63;
    const int lrow = lane & 15, lgrp = lane >> 4;
    const int bx = blockIdx.x;
    const int n = bx % 3;
    const int m0 = (bx / 3) * 32;
    const bool bf = ctl[0] != 0u;
    const u16* w1 = bf ? w1bf : w1cv;
    const u16* w2 = bf ? w2bf : w2cv;
    const f32x4 fz = {0.f, 0.f, 0.f, 0.f};
    const float xmin = decf(ctl[1]), xmax = decf(ctl[2]);
    const float inv = 1.0f / (xmax - xmin);
    const float csh = 0.1f - xmin * inv;

    // ---- Phase A: layer-1 GEMM (rows m0..m0+31, cols 7/6/6/6 per wave) ----
    const int cntw  = wv ? 6 : 7;
    const int cbase = wv ? (16 + 96 * wv) : 0;   // 0 / 112 / 208 / 304
    f32x4 acc1[2][7];
    #pragma unroll
    for (int i = 0; i < 2; ++i)
        #pragma unroll
        for (int j = 0; j < 7; ++j) acc1[i][j] = fz;

    const int rowA = m0 + lrow;
    if (bf) {
        const u16* xg = (const u16*)xr;
        const size_t ar0 = (size_t)rowA * S_N + lgrp * 8;
        const size_t ar1 = ar0 + (size_t)16 * S_N;
        U4 nx0, nx1;
        nx0.u = *(const u32x4*)(xg + ar0);
        nx1.u = *(const u32x4*)(xg + ar1);
        for (int ks = 0; ks < 16; ++ks) {
            U4 a0 = nx0, a1 = nx1;
            if (ks < 15) {
                nx0.u = *(const u32x4*)(xg + ar0 + (ks + 1) * 32);
                nx1.u = *(const u32x4*)(xg + ar1 + (ks + 1) * 32);
            }
            const int k = ks * 32 + lgrp * 8;
            #pragma unroll
            for (int ct = 0; ct < 7; ++ct) {
                if (ct < cntw) {
                    const int col = cbase + ct * 16 + lrow;   // < 400 always
                    U4 b; b.u = *(const u32x4*)(w1 + (size_t)col * S_N + k);
                    acc1[0][ct] = MFMA16(a0.v, b.v, acc1[0][ct]);
                    acc1[1][ct] = MFMA16(a1.v, b.v, acc1[1][ct]);
                }
            }
        }
    } else {
        const f32x4* xf = (const f32x4*)xr;
        const size_t q0 = ((size_t)rowA * S_N + lgrp * 8) >> 2;
        const size_t q1 = q0 + (size_t)16 * S_N / 4;
        f32x4 n0a = xf[q0], n0b = xf[q0 + 1], n1a = xf[q1], n1b = xf[q1 + 1];
        for (int ks = 0; ks < 16; ++ks) {
            f32x4 c0a = n0a, c0b = n0b, c1a = n1a, c1b = n1b;
            if (ks < 15) {
                const size_t o = (size_t)(ks + 1) * 8;
                n0a = xf[q0 + o]; n0b = xf[q0 + o + 1];
                n1a = xf[q1 + o]; n1b = xf[q1 + o + 1];
            }
            U4 a0, a1;
            #pragma unroll
            for (int j = 0; j < 4; ++j) {
                a0.s[j] = f2bfbits(c0a[j]); a0.s[4 + j] = f2bfbits(c0b[j]);
                a1.s[j] = f2bfbits(c1a[j]); a1.s[4 + j] = f2bfbits(c1b[j]);
            }
            const int k = ks * 32 + lgrp * 8;
            #pragma unroll
            for (int ct = 0; ct < 7; ++ct) {
                if (ct < cntw) {
                    const int col = cbase + ct * 16 + lrow;
                    U4 b; b.u = *(const u32x4*)(w1 + (size_t)col * S_N + k);
                    acc1[0][ct] = MFMA16(a0.v, b.v, acc1[0][ct]);
                    acc1[1][ct] = MFMA16(a1.v, b.v, acc1[1][ct]);
                }
            }
        }
    }

    // ---- Phase B: ADF ReLU + mask1 -> pm/pv LDS slabs ----
    #pragma unroll
    for (int ct = 0; ct < 7; ++ct) {
        if (ct < cntw) {
            const int col = cbase + ct * 16 + lrow;
            const float c1 = csh * rs1[col] + b1f[col];
            const float vv = vc1[col];
            #pragma unroll
            for (int r2 = 0; r2 < 2; ++r2)
                #pragma unroll
                for (int r = 0; r < 4; ++r) {
                    const int rl = r2 * 16 + lgrp * 4 + r;
                    float mm = fmaf(inv, acc1[r2][ct][r], c1);
                    float omx, ovx; adf_relu(mm, vv, omx, ovx);
                    const size_t midx = ((size_t)n * B_N + m0 + rl) * H1_N + col;
                    const float mf = bf ? bf2f(((const u16*)m1r)[midx])
                                        : ((const float*)m1r)[midx];
                    pmS[rl * 408 + col] = f2bfbits(omx * mf);
                    pvS[rl * 408 + col] = f2bfbits(ovx * mf * mf);
                }
        }
    }
    __syncthreads();

    // ---- Phase C: layer-2 GEMM over K (R8 form) ----
    f32x4 accM[2][5], accV[2][5];
    #pragma unroll
    for (int i = 0; i < 2; ++i)
        #pragma unroll
        for (int j = 0; j < 5; ++j) { accM[i][j] = fz; accV[i][j] = fz; }

    #pragma unroll 1
    for (int ks = 0; ks < 12; ++ks) {
        const int k0 = ks * 32;
        bf16x8 amf[2], avf[2];
        #pragma unroll
        for (int r2 = 0; r2 < 2; ++r2) {
            const int idx = (r2 * 16 + lrow) * 408 + k0 + lgrp * 8;
            amf[r2] = *(const bf16x8*)(pmS + idx);
            avf[r2] = *(const bf16x8*)(pvS + idx);
        }
        const int kb = k0 + lgrp * 8;
        #pragma unroll
        for (int ct = 0; ct < 5; ++ct) {
            const int col = wv * 80 + ct * 16 + lrow;
            U4 bm, bv; bm.u = 0; bv.u = 0;
            if (col < H2_N) {
                const size_t bidx = (size_t)col * H1_N + kb;
                bm.u = *(const u32x4*)(w2 + bidx);
                bv.u = *(const u32x4*)(w2sqg + bidx);
            }
            accM[0][ct] = MFMA16(amf[0], bm.v, accM[0][ct]);
            accM[1][ct] = MFMA16(amf[1], bm.v, accM[1][ct]);
            accV[0][ct] = MFMA16(avf[0], bv.v, accV[0][ct]);
            accV[1][ct] = MFMA16(avf[1], bv.v, accV[1][ct]);
        }
    }
    {   // tail: k0=384, valid k<400 -> zero lgrp>=2 fragments in regs
        const bool kv = lgrp < 2;
        const int ko = kv ? lgrp * 8 : 0;
        bf16x8 amf[2], avf[2];
        #pragma unroll
        for (int r2 = 0; r2 < 2; ++r2) {
            const int idx = (r2 * 16 + lrow) * 408 + 384 + ko;
            U4 ta, tv;
            ta.v = *(const bf16x8*)(pmS + idx);
            tv.v = *(const bf16x8*)(pvS + idx);
            if (!kv) { ta.u = 0; tv.u = 0; }
            amf[r2] = ta.v; avf[r2] = tv.v;
        }
        const int kb = 384 + lgrp * 8;
        #pragma unroll
        for (int ct = 0; ct < 5; ++ct) {
            const int col = wv * 80 + ct * 16 + lrow;
            U4 bm, bv; bm.u = 0; bv.u = 0;
            if (col < H2_N && kb < H1_N) {
                const size_t bidx = (size_t)col * H1_N + kb;
                bm.u = *(const u32x4*)(w2 + bidx);
                bv.u = *(const u32x4*)(w2sqg + bidx);
            }
            accM[0][ct] = MFMA16(amf[0], bm.v, accM[0][ct]);
            accM[1][ct] = MFMA16(amf[1], bm.v, accM[1][ct]);
            accV[0][ct] = MFMA16(avf[0], bv.v, accV[0][ct]);
            accV[1][ct] = MFMA16(avf[1], bv.v, accV[1][ct]);
        }
    }
    __syncthreads();  // pmS/pvS reads done; slabs about to be overwritten

    // ---- mask2 batch-prefetch: issue all 40 loads before any ADF compute ----
    float msk[2][5][4];
    #pragma unroll
    for (int r2 = 0; r2 < 2; ++r2)
        #pragma unroll
        for (int ct = 0; ct < 5; ++ct) {
            const int col = wv * 80 + ct * 16 + lrow;
            #pragma unroll
            for (int r = 0; r < 4; ++r) {
                const int rl = r2 * 16 + lgrp * 4 + r;
                float mf = 0.0f;
                if (col < H2_N) {
                    const size_t midx = ((size_t)n * B_N + m0 + rl) * H2_N + col;
                    mf = bf ? bf2f(((const u16*)m2r)[midx])
                            : ((const float*)m2r)[midx];
                }
                msk[r2][ct][r] = mf;
            }
        }

    // ---- epilogue: ADF ReLU + mask2 -> LDS slabs ----
    #pragma unroll
    for (int r2 = 0; r2 < 2; ++r2)
        #pragma unroll
        for (int ct = 0; ct < 5; ++ct) {
            const int col = wv * 80 + ct * 16 + lrow;
            const float b2v = (col < H2_N) ? b2f[col] : 0.0f;
            #pragma unroll
            for (int r = 0; r < 4; ++r) {
                const int rl = r2 * 16 + lgrp * 4 + r;
                u16 wm = 0, wvs = 0;
                if (col < H2_N) {
                    float mm = accM[r2][ct][r] + b2v;
                    float vvx = accV[r2][ct][r];
                    float omx, ovx; adf_relu(mm, vvx, omx, ovx);
                    const float mskv = msk[r2][ct][r];
                    wm  = f2bfbits(omx * mskv);
                    wvs = f2bfbits(ovx * mskv * mskv);
                }
                m2s[rl * 328 + col] = wm;
                v2s[rl * 328 + col] = wvs;
            }
        }
    __syncthreads();

    // ---- W3 GEMM: wave task (typ = m/v, rt = row-tile of 16) ----
    {
        const int typ = wv & 1, rt = wv >> 1;
        const u16* slab = typ ? v2s : m2s;
        const u16* w3t  = typ ? w3vg : w3mg;
        f32x4 c3 = fz;
        #pragma unroll
        for (int kk = 0; kk < 10; ++kk) {
            const int aidx = (rt * 16 + lrow) * 328 + kk * 32 + lgrp * 8;
            bf16x8 af = *(const bf16x8*)(slab + aidx);
            U4 bw; bw.u = *(const u32x4*)(w3t + (size_t)lrow * 320 + kk * 32 + lgrp * 8);
            c3 = MFMA16(af, bw.v, c3);
        }
        float* part = typ ? vpart : mpart;
        if (lrow < A_N) {
            #pragma unroll
            for (int r = 0; r < 4; ++r) {
                const int rl = rt * 16 + lgrp * 4 + r;
                part[((size_t)n * B_N + m0 + rl) * 8 + lrow] = c3[r];
            }
        }
    }
}

// ---------------- final combine: mean/var over N=3, 10^x ----------------
__global__ __launch_bounds__(256)
void k_out(const float* __restrict__ mpart, const float* __restrict__ vpart,
           const float* __restrict__ b3f, const u32* __restrict__ ctl,
           void* __restrict__ outr) {
    const size_t idx = (size_t)blockIdx.x * 256 + threadIdx.x;  // [0, 262144)
    const int a = (int)(idx & 7);
    const size_t st = (size_t)B_N * 8;
    const float m0 = mpart[idx], m1 = mpart[st + idx], m2 = mpart[2 * st + idx];
    const float v0 = vpart[idx], v1 = vpart[st + idx], v2 = vpart[2 * st + idx];
    const float md = (m0 + m1 + m2) * (1.0f / 3.0f);
    const float sm2 = (m0 * m0 + m1 * m1 + m2 * m2) * (1.0f / 3.0f);
    const float meanout = md + b3f[a];
    const float vexp = (v0 + v1 + v2) * (1.0f / 3.0f) + sm2 - md * md;
    const float varout = __expf(vexp * 2.302585092994046f);  // 10^x
    const bool bf = ctl[0] != 0u;
    if (bf) {
        ((u16*)outr)[idx] = f2bfbits(meanout);
        ((u16*)outr)[st + idx] = f2bfbits(varout);
    } else {
        ((float*)outr)[idx] = meanout;
        ((float*)outr)[st + idx] = varout;
    }
}

extern "C" void kernel_launch(void* const* d_in, const int* in_sizes, int n_in,
                              void* d_out, int out_size, void* d_ws, size_t ws_size,
                              hipStream_t stream) {
    const void* x     = d_in[0];
    // d_in[1] = x_noise (unused by reference)
    const void* W1    = d_in[2];
    const void* b1    = d_in[3];
    const void* W2    = d_in[4];
    const void* b2    = d_in[5];
    const void* W3    = d_in[6];
    const void* b3    = d_in[7];
    const void* mask1 = d_in[8];
    const void* mask2 = d_in[9];

    char* ws = (char*)d_ws;
    u32*   ctl   = (u32*)(ws + WS_CTL);
    float* b1f   = (float*)(ws + WS_B1F);
    float* b2f   = (float*)(ws + WS_B2F);
    float* b3f   = (float*)(ws + WS_B3F);
    float* rs1   = (float*)(ws + WS_RS1);
    float* vc1   = (float*)(ws + WS_VC1);
    u16*   w3m   = (u16*)(ws + WS_W3M);
    u16*   w3v   = (u16*)(ws + WS_W3V);
    u16*   w2sq  = (u16*)(ws + WS_W2SQ);
    u16*   w2b   = (u16*)(ws + WS_W2B);
    u16*   w1b   = (u16*)(ws + WS_W1B);
    float* mpart = (float*)(ws + WS_MP);
    float* vpart = (float*)(ws + WS_VP);

    k_detect<<<1, 64, 0, stream>>>((const u32*)x, ctl);
    k_weights<<<100, 256, 0, stream>>>(W1, W2, W3, b1, b2, b3, ctl,
                                       w1b, w2b, w2sq, w3m, w3v, b1f, b2f, b3f);
    k_minmax<<<2048, 256, 0, stream>>>(x, ctl);
    k_prep<<<400, 64, 0, stream>>>(W1, ctl, rs1, vc1);
    k_l23f<<<3072, 256, 0, stream>>>(x, (const u16*)W1, w1b, b1f, rs1, vc1,
                                     (const u16*)W2, w2b, w2sq, mask1, mask2,
                                     b2f, w3m, w3v, ctl, mpart, vpart);
    k_out<<<1024, 256, 0, stream>>>(mpart, vpart, b3f, ctl, d_out);
}

// Round 11
// 652.781 us; speedup vs baseline: 1.2676x; 1.2676x over previous
//
#include <hip/hip_runtime.h>

// ---------------------------------------------------------------------------
// UAActor MC-dropout ADF MLP, MI355X/gfx950.
// B=32768 S=512 H1=400 H2=300 A=8 N=3.  Inputs bf16 (runtime-detected; f32
// fallback).  Internal GEMM operands bf16.
//
// R15: R8 (658us best) + launch-count 7 -> 5.  R14's A/B proved k_l1 is only
// ~60-95us (at its byte floor) and k_l23 sits at the ~950 GB/s wall with
// near-minimal bytes -> the largest remaining term is ~30us/launch dispatch
// overhead (~250us across 7 launches).  k_weights+k_prep+k_minmax merged
// into one k_prepall (grid 2248 = 100 weights | 100 prep | 2048 minmax);
// k_detect stays first (writes ctl[0] + inits min/max identities, so no
// intra-kernel init/atomic race).  All math bit-identical to R8.
// R13/R14's layer-1 fusion REVERTED (serialized phases broke MLP, +169us).
// ---------------------------------------------------------------------------

typedef unsigned short u16;
typedef unsigned int u32;
typedef float f32x4 __attribute__((ext_vector_type(4)));
typedef __bf16 bf16x8 __attribute__((ext_vector_type(8)));
typedef u32 u32x4 __attribute__((ext_vector_type(4)));

union U4 { u32x4 u; bf16x8 v; u16 s[8]; };

#define MFMA16(a, b, c) __builtin_amdgcn_mfma_f32_16x16x32_bf16(a, b, c, 0, 0, 0)

#define B_N 32768
#define S_N 512
#define H1_N 400
#define H2_N 300
#define A_N 8

__device__ __forceinline__ float bf2f(u16 h) {
    union { float f; u32 u; } c; c.u = ((u32)h) << 16; return c.f;
}
// Native HW convert (RNE, v_cvt_pk_bf16_f32 when paired).
__device__ __forceinline__ u16 f2bfbits(float f) {
    union { __bf16 h; u16 u; } c; c.h = (__bf16)f; return c.u;
}
__device__ __forceinline__ u32 encf(float f) {
    u32 u = __float_as_uint(f);
    return (u & 0x80000000u) ? ~u : (u | 0x80000000u);
}
__device__ __forceinline__ float decf(u32 e) {
    u32 u = (e >> 31) ? (e & 0x7FFFFFFFu) : ~e;
    return __uint_as_float(u);
}

// ADF ReLU moment matching; shares one exp between erf (A&S 7.1.26) and pdf.
__device__ __forceinline__ void adf_relu(float m, float v, float& om, float& ov) {
    v = fmaxf(v, 1e-12f);
    float rstd = rsqrtf(v);
    float stdv = v * rstd;
    float r = m * rstd;
    float e = __expf(-0.5f * r * r);
    float ar = fabsf(r) * 0.70710678118654752f;
    float t = __builtin_amdgcn_rcpf(fmaf(0.3275911f, ar, 1.0f));
    float poly = t * (0.254829592f + t * (-0.284496736f + t * (1.421413741f +
                  t * (-1.453152027f + t * 1.061405429f))));
    float erfa = 1.0f - poly * e;
    float erfv = (r < 0.0f) ? -erfa : erfa;
    float cdf = 0.5f * (1.0f + erfv);
    float pdf = 0.3989422804014327f * e;
    om = fmaf(m, cdf, stdv * pdf);
    ov = fmaf(m * m + v, cdf, m * stdv * pdf) - om * om;
    ov = fmaxf(ov, 0.0f);
}

// ---------------- workspace layout (bytes) ----------------
#define WS_CTL    0u          // u32[16]: [0]=is_bf16, [1]=encmin, [2]=encmax
#define WS_B1F    64u         // 400 f32
#define WS_B2F    1664u       // 300 f32
#define WS_B3F    2880u       // 8 f32
#define WS_RS1    2944u       // 400 f32
#define WS_VC1    4544u       // 400 f32
#define WS_W3M    6144u       // 16*320 bf16 (zero padded)
#define WS_W3V    16384u      // 16*320 bf16 (squares)
#define WS_W2SQ   26624u      // 300*400 bf16
#define WS_W2B    266624u     // 300*400 bf16 (f32 mode: converted W2)
#define WS_W1B    506624u     // 400*512 bf16 (f32 mode: converted W1)
#define WS_OMOV   916224u     // 32768*400 u32 (om lo16 | ov hi16), end 53345024
#define WS_MP     53345024u   // 3*32768*8 f32 per-n mean partials (3145728 B)
#define WS_VP     56490752u   // 3*32768*8 f32 per-n var partials, end 59636480

// ---------------- dtype detect + ctl init ----------------
__global__ void k_detect(const u32* __restrict__ xw, u32* __restrict__ ctl) {
    if (threadIdx.x == 0) {
        int votes = 0;
        for (int i = 0; i < 64; ++i) {
            u32 u = xw[i * 997];
            u32 e = (u >> 7) & 0xFFu;
            votes += (e >= 100u && e <= 145u) ? 1 : 0;
        }
        ctl[0] = (votes >= 40) ? 1u : 0u;
        ctl[1] = 0xFFFFFFFFu;   // encoded min slot
        ctl[2] = 0u;            // encoded max slot
    }
}

// ---------------- merged prep: weights | W1 row stats | x min/max ----------
// grid 2248: bid<100 -> weights prep; 100<=bid<200 -> W1 row sums (4 rows
// per block, one per wave); bid>=200 -> x min/max (2048 grid-stride blocks).
__global__ __launch_bounds__(256)
void k_prepall(const void* __restrict__ xr,
               const void* __restrict__ w1r, const void* __restrict__ w2r,
               const void* __restrict__ w3r, const void* __restrict__ b1r,
               const void* __restrict__ b2r, const void* __restrict__ b3r,
               u32* __restrict__ ctl,
               u16* __restrict__ w1b, u16* __restrict__ w2b,
               u16* __restrict__ w2sq, u16* __restrict__ w3m,
               u16* __restrict__ w3v, float* __restrict__ b1f,
               float* __restrict__ b2f, float* __restrict__ b3f,
               float* __restrict__ rs1, float* __restrict__ vc1) {
    const bool bf = ctl[0] != 0u;
    const int bid = blockIdx.x;
    const int tid = threadIdx.x, lane = tid & 63, wv = tid >> 6;

    if (bid < 100) {
        // ---- weights prep (identical to R8 k_weights) ----
        const int t = bid * 256 + tid;
        if (t < (H2_N * H1_N / 8)) {  // W2 -> w2sq (+ W2B in f32 mode)
            float f[8];
            if (bf) {
                U4 d; d.u = *(const u32x4*)((const u16*)w2r + (size_t)t * 8);
                #pragma unroll
                for (int j = 0; j < 8; ++j) f[j] = bf2f(d.s[j]);
            } else {
                f32x4 a = *((const f32x4*)w2r + (size_t)t * 2);
                f32x4 b = *((const f32x4*)w2r + (size_t)t * 2 + 1);
                #pragma unroll
                for (int j = 0; j < 4; ++j) { f[j] = a[j]; f[4 + j] = b[j]; }
            }
            u16 sq[8], cv[8];
            #pragma unroll
            for (int j = 0; j < 8; ++j) { sq[j] = f2bfbits(f[j] * f[j]); cv[j] = f2bfbits(f[j]); }
            *(u32x4*)(w2sq + (size_t)t * 8) = *(u32x4*)sq;
            if (!bf) *(u32x4*)(w2b + (size_t)t * 8) = *(u32x4*)cv;
        }
        if (!bf && t < (H1_N * S_N / 8)) {  // W1 convert (f32 mode only)
            f32x4 a = *((const f32x4*)w1r + (size_t)t * 2);
            f32x4 b = *((const f32x4*)w1r + (size_t)t * 2 + 1);
            u16 cv[8];
            #pragma unroll
            for (int j = 0; j < 4; ++j) { cv[j] = f2bfbits(a[j]); cv[4 + j] = f2bfbits(b[j]); }
            *(u32x4*)(w1b + (size_t)t * 8) = *(u32x4*)cv;
        }
        if (t < 16 * 320) {  // padded W3 tables
            int col = t / 320, k = t - col * 320;
            float f = 0.0f;
            if (col < A_N && k < H2_N)
                f = bf ? bf2f(((const u16*)w3r)[col * H2_N + k]) : ((const float*)w3r)[col * H2_N + k];
            w3m[t] = f2bfbits(f);
            w3v[t] = f2bfbits(f * f);
        }
        if (t < H1_N) b1f[t] = bf ? bf2f(((const u16*)b1r)[t]) : ((const float*)b1r)[t];
        if (t < H2_N) b2f[t] = bf ? bf2f(((const u16*)b2r)[t]) : ((const float*)b2r)[t];
        if (t < A_N)  b3f[t] = bf ? bf2f(((const u16*)b3r)[t]) : ((const float*)b3r)[t];
    } else if (bid < 200) {
        // ---- W1 row sums + variance constant (4 rows/block, 1/wave) ----
        const int h = (bid - 100) * 4 + wv;    // < 400
        float f[8];
        if (bf) {
            U4 d; d.u = *(const u32x4*)((const u16*)w1r + (size_t)h * S_N + lane * 8);
            #pragma unroll
            for (int j = 0; j < 8; ++j) f[j] = bf2f(d.s[j]);
        } else {
            f32x4 a = *((const f32x4*)w1r + (size_t)h * 128 + lane * 2);
            f32x4 b = *((const f32x4*)w1r + (size_t)h * 128 + lane * 2 + 1);
            #pragma unroll
            for (int j = 0; j < 4; ++j) { f[j] = a[j]; f[4 + j] = b[j]; }
        }
        float s1 = 0.f, s2 = 0.f;
        #pragma unroll
        for (int j = 0; j < 8; ++j) { s1 += f[j]; s2 += f[j] * f[j]; }
        #pragma unroll
        for (int off = 32; off >= 1; off >>= 1) {
            s1 += __shfl_xor(s1, off);
            s2 += __shfl_xor(s2, off);
        }
        if (lane == 0) { rs1[h] = s1; vc1[h] = 2.0001f * s2; }
    } else {
        // ---- global min/max of x (2048 grid-stride blocks) ----
        float mn = 3.0e38f, mx = -3.0e38f;
        const int idx = (bid - 200) * 256 + tid;
        if (bf) {
            const u16* xg = (const u16*)xr;
            for (int i = idx; i < (B_N * S_N / 8); i += 2048 * 256) {
                U4 d; d.u = *(const u32x4*)(xg + (size_t)i * 8);
                #pragma unroll
                for (int j = 0; j < 8; ++j) {
                    float f = bf2f(d.s[j]);
                    mn = fminf(mn, f); mx = fmaxf(mx, f);
                }
            }
        } else {
            const f32x4* xf = (const f32x4*)xr;
            for (int i = idx; i < (B_N * S_N / 4); i += 2048 * 256) {
                f32x4 d = xf[i];
                #pragma unroll
                for (int j = 0; j < 4; ++j) {
                    mn = fminf(mn, d[j]); mx = fmaxf(mx, d[j]);
                }
            }
        }
        #pragma unroll
        for (int off = 32; off >= 1; off >>= 1) {
            mn = fminf(mn, __shfl_xor(mn, off));
            mx = fmaxf(mx, __shfl_xor(mx, off));
        }
        __shared__ float rmn[4], rmx[4];
        if (lane == 0) { rmn[wv] = mn; rmx[wv] = mx; }
        __syncthreads();
        if (tid == 0) {
            for (int w = 1; w < 4; ++w) { mn = fminf(mn, rmn[w]); mx = fmaxf(mx, rmx[w]); }
            atomicMin(&ctl[1], encf(mn));
            atomicMax(&ctl[2], encf(mx));
        }
    }
}

// ---------------- layer1 GEMM + ADF ReLU ----------------
// grid (256, 4): 128 rows x 112 cols per block, 4 waves (wave = 32 rows).
// A-operand 1-step register double-buffer; packed omov dword stores.
__global__ __launch_bounds__(256, 4)
void k_l1(const void* __restrict__ xr, const u16* __restrict__ w1bf,
          const u16* __restrict__ w1cv, const float* __restrict__ b1f,
          const float* __restrict__ rs1, const float* __restrict__ vc1,
          const u32* __restrict__ ctl, u32* __restrict__ omovg) {
    const int tid = threadIdx.x, wv = tid >> 6, lane = tid & 63;
    const int lrow = lane & 15, lgrp = lane >> 4;
    const int m0 = blockIdx.x * 128;
    const int n0 = blockIdx.y * 112;
    const bool bf = ctl[0] != 0u;
    const u16* w1 = bf ? w1bf : w1cv;
    const float xmin = decf(ctl[1]), xmax = decf(ctl[2]);
    const float inv = 1.0f / (xmax - xmin);
    const float csh = 0.1f - xmin * inv;

    const f32x4 fz = {0.f, 0.f, 0.f, 0.f};
    f32x4 acc[2][7];
    #pragma unroll
    for (int i = 0; i < 2; ++i)
        #pragma unroll
        for (int j = 0; j < 7; ++j) acc[i][j] = fz;

    const int rowA = m0 + wv * 32 + lrow;
    if (bf) {
        const u16* xg = (const u16*)xr;
        const size_t ar0 = (size_t)rowA * S_N + lgrp * 8;
        const size_t ar1 = ar0 + (size_t)16 * S_N;
        U4 nx0, nx1;
        nx0.u = *(const u32x4*)(xg + ar0);
        nx1.u = *(const u32x4*)(xg + ar1);
        for (int ks = 0; ks < 16; ++ks) {
            U4 a0 = nx0, a1 = nx1;
            if (ks < 15) {
                nx0.u = *(const u32x4*)(xg + ar0 + (ks + 1) * 32);
                nx1.u = *(const u32x4*)(xg + ar1 + (ks + 1) * 32);
            }
            const int k = ks * 32 + lgrp * 8;
            #pragma unroll
            for (int ct = 0; ct < 7; ++ct) {
                const int col = n0 + ct * 16 + lrow;
                U4 b; b.u = 0;
                if (col < H1_N) b.u = *(const u32x4*)(w1 + (size_t)col * S_N + k);
                acc[0][ct] = MFMA16(a0.v, b.v, acc[0][ct]);
                acc[1][ct] = MFMA16(a1.v, b.v, acc[1][ct]);
            }
        }
    } else {
        const f32x4* xf = (const f32x4*)xr;
        const size_t q0 = ((size_t)rowA * S_N + lgrp * 8) >> 2;
        const size_t q1 = q0 + (size_t)16 * S_N / 4;
        f32x4 n0a = xf[q0], n0b = xf[q0 + 1], n1a = xf[q1], n1b = xf[q1 + 1];
        for (int ks = 0; ks < 16; ++ks) {
            f32x4 c0a = n0a, c0b = n0b, c1a = n1a, c1b = n1b;
            if (ks < 15) {
                const size_t o = (size_t)(ks + 1) * 8;
                n0a = xf[q0 + o]; n0b = xf[q0 + o + 1];
                n1a = xf[q1 + o]; n1b = xf[q1 + o + 1];
            }
            U4 a0, a1;
            #pragma unroll
            for (int j = 0; j < 4; ++j) {
                a0.s[j] = f2bfbits(c0a[j]); a0.s[4 + j] = f2bfbits(c0b[j]);
                a1.s[j] = f2bfbits(c1a[j]); a1.s[4 + j] = f2bfbits(c1b[j]);
            }
            const int k = ks * 32 + lgrp * 8;
            #pragma unroll
            for (int ct = 0; ct < 7; ++ct) {
                const int col = n0 + ct * 16 + lrow;
                U4 b; b.u = 0;
                if (col < H1_N) b.u = *(const u32x4*)(w1 + (size_t)col * S_N + k);
                acc[0][ct] = MFMA16(a0.v, b.v, acc[0][ct]);
                acc[1][ct] = MFMA16(a1.v, b.v, acc[1][ct]);
            }
        }
    }
    #pragma unroll
    for (int ct = 0; ct < 7; ++ct) {
        const int col = n0 + ct * 16 + lrow;
        if (col < H1_N) {
            const float c1 = csh * rs1[col] + b1f[col];
            const float vv = vc1[col];
            #pragma unroll
            for (int r2 = 0; r2 < 2; ++r2)
                #pragma unroll
                for (int r = 0; r < 4; ++r) {
                    const int row = m0 + wv * 32 + r2 * 16 + lgrp * 4 + r;
                    float mm = fmaf(inv, acc[r2][ct][r], c1);
                    float omx, ovx; adf_relu(mm, vv, omx, ovx);
                    omovg[(size_t)row * H1_N + col] =
                        (u32)f2bfbits(omx) | ((u32)f2bfbits(ovx) << 16);
                }
        }
    }
}

// ---------------- layers 2+3 fused, one (n, row-tile) per block ----------------
// grid 3072 = 1024 row-tiles x 3 MC samples, n fastest (omov L2/L3 reuse
// across the 3 co-dispatched siblings). BM=32 (R6/R8 geometry). Transient
// packet regs, 3 barriers, mask2 batch-prefetch at epilogue top, f32
// partials out. 256 thr, wave = 80-col group.
__global__ __launch_bounds__(256, 3)
void k_l23(const u32* __restrict__ omovg, const u16* __restrict__ w2bf,
           const u16* __restrict__ w2cv, const u16* __restrict__ w2sqg,
           const void* __restrict__ m1r, const void* __restrict__ m2r,
           const float* __restrict__ b2f,
           const u16* __restrict__ w3mg, const u16* __restrict__ w3vg,
           const u32* __restrict__ ctl, float* __restrict__ mpart,
           float* __restrict__ vpart) {
    __shared__ __align__(16) unsigned char smem[52224];
    u16* pmS = (u16*)smem;                 // [32][408] bf16 products
    u16* pvS = (u16*)(smem + 26112);       // [32][408]
    u16* m2s = (u16*)smem;                 // [32][328] (aliases pmS, post-GEMM)
    u16* v2s = (u16*)(smem + 26112);       // [32][328] (aliases pvS)

    const int tid = threadIdx.x;
    const int wv = tid >> 6, lane = tid & 63;
    const int lrow = lane & 15, lgrp = lane >> 4;
    const int bx = blockIdx.x;
    const int n = bx % 3;
    const int m0 = (bx / 3) * 32;
    const bool bf = ctl[0] != 0u;
    const u16* w2 = bf ? w2bf : w2cv;
    const f32x4 fz = {0.f, 0.f, 0.f, 0.f};

    // ---- products: omov * mask1[n] -> LDS (transient regs, unroll 2) ----
    #pragma unroll 2
    for (int p = 0; p < 7; ++p) {
        const int c = tid + p * 256;
        if (c < 1600) {
            const int row = c / 50, kc = (c - row * 50) * 8;
            const size_t base = (size_t)(m0 + row) * H1_N + kc;
            u32x4 o0 = *(const u32x4*)(omovg + base);
            u32x4 o1 = *(const u32x4*)(omovg + base + 4);
            const size_t mb = ((size_t)n * B_N + m0 + row) * H1_N + kc;
            u32x4 k0 = {0, 0, 0, 0}, k1 = {0, 0, 0, 0};
            if (bf) {
                k0 = *(const u32x4*)((const u16*)m1r + mb);
            } else {
                k0 = *(const u32x4*)((const float*)m1r + mb);
                k1 = *(const u32x4*)((const float*)m1r + mb + 4);
            }
            u16 pm[8], pv[8];
            #pragma unroll
            for (int j = 0; j < 8; ++j) {
                const u32 w = (j < 4) ? o0[j] : o1[j - 4];
                const float omf = __uint_as_float(w << 16);
                const float ovf = __uint_as_float(w & 0xFFFF0000u);
                float mf;
                if (bf) {
                    const u32 mw = k0[j >> 1];
                    mf = bf2f((u16)((j & 1) ? (mw >> 16) : (mw & 0xFFFFu)));
                } else {
                    mf = __uint_as_float((j < 4) ? k0[j] : k1[j - 4]);
                }
                pm[j] = f2bfbits(omf * mf);
                pv[j] = f2bfbits(ovf * mf * mf);
            }
            *(u32x4*)(pmS + row * 408 + kc) = *(u32x4*)pm;
            *(u32x4*)(pvS + row * 408 + kc) = *(u32x4*)pv;
        }
    }
    __syncthreads();

    // ---- barrier-free GEMM over K ----
    f32x4 accM[2][5], accV[2][5];
    #pragma unroll
    for (int i = 0; i < 2; ++i)
        #pragma unroll
        for (int j = 0; j < 5; ++j) { accM[i][j] = fz; accV[i][j] = fz; }

    #pragma unroll 1
    for (int ks = 0; ks < 12; ++ks) {
        const int k0 = ks * 32;
        bf16x8 amf[2], avf[2];
        #pragma unroll
        for (int r2 = 0; r2 < 2; ++r2) {
            const int idx = (r2 * 16 + lrow) * 408 + k0 + lgrp * 8;
            amf[r2] = *(const bf16x8*)(pmS + idx);
            avf[r2] = *(const bf16x8*)(pvS + idx);
        }
        const int kb = k0 + lgrp * 8;
        #pragma unroll
        for (int ct = 0; ct < 5; ++ct) {
            const int col = wv * 80 + ct * 16 + lrow;
            U4 bm, bv; bm.u = 0; bv.u = 0;
            if (col < H2_N) {
                const size_t bidx = (size_t)col * H1_N + kb;
                bm.u = *(const u32x4*)(w2 + bidx);
                bv.u = *(const u32x4*)(w2sqg + bidx);
            }
            accM[0][ct] = MFMA16(amf[0], bm.v, accM[0][ct]);
            accM[1][ct] = MFMA16(amf[1], bm.v, accM[1][ct]);
            accV[0][ct] = MFMA16(avf[0], bv.v, accV[0][ct]);
            accV[1][ct] = MFMA16(avf[1], bv.v, accV[1][ct]);
        }
    }
    {   // tail: k0=384, valid k<400 -> zero lgrp>=2 fragments in regs
        const bool kv = lgrp < 2;
        const int ko = kv ? lgrp * 8 : 0;
        bf16x8 amf[2], avf[2];
        #pragma unroll
        for (int r2 = 0; r2 < 2; ++r2) {
            const int idx = (r2 * 16 + lrow) * 408 + 384 + ko;
            U4 ta, tv;
            ta.v = *(const bf16x8*)(pmS + idx);
            tv.v = *(const bf16x8*)(pvS + idx);
            if (!kv) { ta.u = 0; tv.u = 0; }
            amf[r2] = ta.v; avf[r2] = tv.v;
        }
        const int kb = 384 + lgrp * 8;
        #pragma unroll
        for (int ct = 0; ct < 5; ++ct) {
            const int col = wv * 80 + ct * 16 + lrow;
            U4 bm, bv; bm.u = 0; bv.u = 0;
            if (col < H2_N && kb < H1_N) {
                const size_t bidx = (size_t)col * H1_N + kb;
                bm.u = *(const u32x4*)(w2 + bidx);
                bv.u = *(const u32x4*)(w2sqg + bidx);
            }
            accM[0][ct] = MFMA16(amf[0], bm.v, accM[0][ct]);
            accM[1][ct] = MFMA16(amf[1], bm.v, accM[1][ct]);
            accV[0][ct] = MFMA16(avf[0], bv.v, accV[0][ct]);
            accV[1][ct] = MFMA16(avf[1], bv.v, accV[1][ct]);
        }
    }
    __syncthreads();  // pmS/pvS reads done; slabs about to be overwritten

    // ---- mask2 batch-prefetch: issue all 40 loads before any ADF compute ----
    float msk[2][5][4];
    #pragma unroll
    for (int r2 = 0; r2 < 2; ++r2)
        #pragma unroll
        for (int ct = 0; ct < 5; ++ct) {
            const int col = wv * 80 + ct * 16 + lrow;
            #pragma unroll
            for (int r = 0; r < 4; ++r) {
                const int rl = r2 * 16 + lgrp * 4 + r;
                float mf = 0.0f;
                if (col < H2_N) {
                    const size_t midx = ((size_t)n * B_N + m0 + rl) * H2_N + col;
                    mf = bf ? bf2f(((const u16*)m2r)[midx])
                            : ((const float*)m2r)[midx];
                }
                msk[r2][ct][r] = mf;
            }
        }

    // ---- epilogue: ADF ReLU + mask2 -> LDS slabs ----
    #pragma unroll
    for (int r2 = 0; r2 < 2; ++r2)
        #pragma unroll
        for (int ct = 0; ct < 5; ++ct) {
            const int col = wv * 80 + ct * 16 + lrow;
            const float b2v = (col < H2_N) ? b2f[col] : 0.0f;
            #pragma unroll
            for (int r = 0; r < 4; ++r) {
                const int rl = r2 * 16 + lgrp * 4 + r;
                u16 wm = 0, wvs = 0;
                if (col < H2_N) {
                    float mm = accM[r2][ct][r] + b2v;
                    float vvx = accV[r2][ct][r];
                    float omx, ovx; adf_relu(mm, vvx, omx, ovx);
                    const float mskv = msk[r2][ct][r];
                    wm  = f2bfbits(omx * mskv);
                    wvs = f2bfbits(ovx * mskv * mskv);
                }
                m2s[rl * 328 + col] = wm;
                v2s[rl * 328 + col] = wvs;
            }
        }
    __syncthreads();

    // ---- W3 GEMM: wave task (typ = m/v, rt = row-tile of 16) ----
    {
        const int typ = wv & 1, rt = wv >> 1;
        const u16* slab = typ ? v2s : m2s;
        const u16* w3t  = typ ? w3vg : w3mg;
        f32x4 c3 = fz;
        #pragma unroll
        for (int kk = 0; kk < 10; ++kk) {
            const int aidx = (rt * 16 + lrow) * 328 + kk * 32 + lgrp * 8;
            bf16x8 af = *(const bf16x8*)(slab + aidx);
            U4 bw; bw.u = *(const u32x4*)(w3t + (size_t)lrow * 320 + kk * 32 + lgrp * 8);
            c3 = MFMA16(af, bw.v, c3);
        }
        float* part = typ ? vpart : mpart;
        if (lrow < A_N) {
            #pragma unroll
            for (int r = 0; r < 4; ++r) {
                const int rl = rt * 16 + lgrp * 4 + r;
                part[((size_t)n * B_N + m0 + rl) * 8 + lrow] = c3[r];
            }
        }
    }
}

// ---------------- final combine: mean/var over N=3, 10^x ----------------
__global__ __launch_bounds__(256)
void k_out(const float* __restrict__ mpart, const float* __restrict__ vpart,
           const float* __restrict__ b3f, const u32* __restrict__ ctl,
           void* __restrict__ outr) {
    const size_t idx = (size_t)blockIdx.x * 256 + threadIdx.x;  // [0, 262144)
    const int a = (int)(idx & 7);
    const size_t st = (size_t)B_N * 8;
    const float m0 = mpart[idx], m1 = mpart[st + idx], m2 = mpart[2 * st + idx];
    const float v0 = vpart[idx], v1 = vpart[st + idx], v2 = vpart[2 * st + idx];
    const float md = (m0 + m1 + m2) * (1.0f / 3.0f);
    const float sm2 = (m0 * m0 + m1 * m1 + m2 * m2) * (1.0f / 3.0f);
    const float meanout = md + b3f[a];
    const float vexp = (v0 + v1 + v2) * (1.0f / 3.0f) + sm2 - md * md;
    const float varout = __expf(vexp * 2.302585092994046f);  // 10^x
    const bool bf = ctl[0] != 0u;
    if (bf) {
        ((u16*)outr)[idx] = f2bfbits(meanout);
        ((u16*)outr)[st + idx] = f2bfbits(varout);
    } else {
        ((float*)outr)[idx] = meanout;
        ((float*)outr)[st + idx] = varout;
    }
}

extern "C" void kernel_launch(void* const* d_in, const int* in_sizes, int n_in,
                              void* d_out, int out_size, void* d_ws, size_t ws_size,
                              hipStream_t stream) {
    const void* x     = d_in[0];
    // d_in[1] = x_noise (unused by reference)
    const void* W1    = d_in[2];
    const void* b1    = d_in[3];
    const void* W2    = d_in[4];
    const void* b2    = d_in[5];
    const void* W3    = d_in[6];
    const void* b3    = d_in[7];
    const void* mask1 = d_in[8];
    const void* mask2 = d_in[9];

    char* ws = (char*)d_ws;
    u32*   ctl   = (u32*)(ws + WS_CTL);
    float* b1f   = (float*)(ws + WS_B1F);
    float* b2f   = (float*)(ws + WS_B2F);
    float* b3f   = (float*)(ws + WS_B3F);
    float* rs1   = (float*)(ws + WS_RS1);
    float* vc1   = (float*)(ws + WS_VC1);
    u16*   w3m   = (u16*)(ws + WS_W3M);
    u16*   w3v   = (u16*)(ws + WS_W3V);
    u16*   w2sq  = (u16*)(ws + WS_W2SQ);
    u16*   w2b   = (u16*)(ws + WS_W2B);
    u16*   w1b   = (u16*)(ws + WS_W1B);
    u32*   omov  = (u32*)(ws + WS_OMOV);
    float* mpart = (float*)(ws + WS_MP);
    float* vpart = (float*)(ws + WS_VP);

    k_detect<<<1, 64, 0, stream>>>((const u32*)x, ctl);
    k_prepall<<<2248, 256, 0, stream>>>(x, W1, W2, W3, b1, b2, b3, ctl,
                                        w1b, w2b, w2sq, w3m, w3v,
                                        b1f, b2f, b3f, rs1, vc1);
    k_l1<<<dim3(256, 4), 256, 0, stream>>>(x, (const u16*)W1, w1b, b1f, rs1, vc1,
                                           ctl, omov);
    k_l23<<<3072, 256, 0, stream>>>(omov, (const u16*)W2, w2b, w2sq, mask1, mask2,
                                    b2f, w3m, w3v, ctl, mpart, vpart);
    k_out<<<1024, 256, 0, stream>>>(mpart, vpart, b3f, ctl, d_out);
}